// Round 4
// baseline (304.943 us; speedup 1.0000x reference)
//
#include <hip/hip_runtime.h>
#include <hip/hip_bf16.h>

#define D 45
#define LSEQ 4096
#define NB 8
#define U 45
#define FH 128
#define KP 48          // padded K row (floats) for aligned s_load merging
#define SPLIT 4        // s-range quarters for qkmax
constexpr float LN_EPS = 1e-12f;

// ---------------------------------------------------------------------------
// Kernel 1:
//   z=0: Xt[b][d][l] = x[b][l][d]              (d-major, for coalesced q loads)
//   z=1: Ksm[b][s][0..47] = gathered K row     (s-major, 192B padded rows)
// ---------------------------------------------------------------------------
__global__ void transpose_kernel(const float* __restrict__ x, const int* __restrict__ idx,
                                 float* __restrict__ Xt, float* __restrict__ Ksm) {
  const int b = blockIdx.y;
  const int z = blockIdx.z;
  const int r0 = blockIdx.x * 64;
  const float* xb = x + (size_t)b * LSEQ * D;
  if (z == 0) {
    __shared__ float tile[D][65];
    for (int i = threadIdx.x; i < 64 * D; i += 256) {
      int j = i / D, d = i - j * D;
      tile[d][j] = xb[(size_t)(r0 + j) * D + d];
    }
    __syncthreads();
    float* dst = Xt + (size_t)b * D * LSEQ + r0;
    for (int i = threadIdx.x; i < D * 64; i += 256) {
      int d = i >> 6, j = i & 63;
      dst[(size_t)d * LSEQ + j] = tile[d][j];
    }
  } else {
    float* kb = Ksm + ((size_t)b * LSEQ + r0) * KP;
    for (int i = threadIdx.x; i < 64 * KP; i += 256) {
      int j = i / KP, d = i - j * KP;
      int row = idx[r0 + j];
      kb[i] = (d < D) ? xb[(size_t)row * D + d] : 0.0f;
    }
  }
}

// ---------------------------------------------------------------------------
// Kernel 2: Ksum[b][d] = sum_s Ksm[b][s][d]   (deterministic, no atomics)
// ---------------------------------------------------------------------------
__global__ void ksum_kernel(const float* __restrict__ Ksm, float* __restrict__ Ksum) {
  __shared__ float sAcc[256][D + 1];
  const int b = blockIdx.x;
  const int tid = threadIdx.x;
  float acc[D];
#pragma unroll
  for (int d = 0; d < D; ++d) acc[d] = 0.f;
  const float* kb = Ksm + (size_t)b * LSEQ * KP;
  for (int s = tid; s < LSEQ; s += 256) {
    const float* kr = kb + (size_t)s * KP;
#pragma unroll
    for (int d = 0; d < D; ++d) acc[d] += kr[d];
  }
#pragma unroll
  for (int d = 0; d < D; ++d) sAcc[tid][d] = acc[d];
  __syncthreads();
  for (int st = 128; st >= 1; st >>= 1) {
    if (tid < st)
      for (int d = 0; d < D; ++d) sAcc[tid][d] += sAcc[tid + st][d];
    __syncthreads();
  }
  if (tid < D) Ksum[b * D + tid] = sAcc[0][tid];
}

// ---------------------------------------------------------------------------
// Kernel 3 (HOT): Mpart[q][b][l] = max over s-quarter of dot(x[b,l,:], Ks[s,:])
// Q in registers (2 rows/lane), K broadcast via SGPR (scalar loads — the K
// pointer is wave-uniform thanks to readfirstlane). No LDS in the inner loop.
// ---------------------------------------------------------------------------
__global__ __launch_bounds__(256, 4) void qkmax_kernel(const float* __restrict__ Xt,
                                                       const float* __restrict__ Ksm,
                                                       float* __restrict__ Mpart) {
  __shared__ float red[4][128];
  const int b = blockIdx.y;
  const int quarter = blockIdx.z;
  const int l0 = blockIdx.x * 128;
  const int tid = threadIdx.x;
  const int lane = tid & 63;
  const int w = __builtin_amdgcn_readfirstlane(tid >> 6);  // uniform wave id

  // q rows in registers: lane owns l0+lane and l0+64+lane
  float q0[D], q1[D];
  const float* XtB = Xt + (size_t)b * D * LSEQ;
#pragma unroll
  for (int d = 0; d < D; ++d) {
    q0[d] = XtB[(size_t)d * LSEQ + l0 + lane];
    q1[d] = XtB[(size_t)d * LSEQ + l0 + 64 + lane];
  }

  // this wave's s-range: 256 keys
  const float* kb = Ksm + ((size_t)b * LSEQ + quarter * (LSEQ / SPLIT) + w * 256) * KP;
  float m0 = -INFINITY, m1 = -INFINITY;
  for (int s = 0; s < 256; ++s) {
    const float* kr = kb + (size_t)s * KP;  // wave-uniform -> s_load
    float a0 = 0.f, a1 = 0.f, c0 = 0.f, c1 = 0.f;  // 4 independent chains
#pragma unroll
    for (int d = 0; d < 22; ++d) {
      a0 = fmaf(q0[d], kr[d], a0);
      c0 = fmaf(q1[d], kr[d], c0);
    }
#pragma unroll
    for (int d = 22; d < D; ++d) {
      a1 = fmaf(q0[d], kr[d], a1);
      c1 = fmaf(q1[d], kr[d], c1);
    }
    m0 = fmaxf(m0, a0 + a1);
    m1 = fmaxf(m1, c0 + c1);
  }

  // combine the 4 waves (each covered a different 256-key slice)
  red[w][lane] = m0;
  red[w][64 + lane] = m1;
  __syncthreads();
  if (tid < 128) {
    float m = fmaxf(fmaxf(red[0][tid], red[1][tid]), fmaxf(red[2][tid], red[3][tid]));
    Mpart[((size_t)quarter * NB + b) * LSEQ + l0 + tid] = m;
  }
}

// ---------------------------------------------------------------------------
// Kernel 4: M = max_q(Mpart) - dot(q, Ksum)/L ; exact top-45 via 8-bit MSB
// radix-select. Tie semantics identical to jax.lax.top_k (value desc, index
// asc). Also gathers the selected Q rows into Qg[b][u][d].
// ---------------------------------------------------------------------------
__global__ __launch_bounds__(256) void topk_kernel(const float* __restrict__ x,
                                                   const float* __restrict__ Xt,
                                                   const float* __restrict__ Ksum,
                                                   const float* __restrict__ Mpart,
                                                   float* __restrict__ Qg) {
  __shared__ float ks[D];
  __shared__ int hist[256];
  __shared__ int wsum[4];
  __shared__ int bin_s, need_s, cntG_s, cntEq_s, minv_s;
  __shared__ unsigned long long cand[U];
  __shared__ int eqIdx[LSEQ];
  __shared__ int sel[U];
  const int b = blockIdx.x;
  const int tid = threadIdx.x;
  const int lane = tid & 63, wv = tid >> 6;

  if (tid < D) ks[tid] = Ksum[b * D + tid];
  __syncthreads();

  // 1. compute keys (monotonic map of M values), kept in registers
  uint32_t kreg[16];
  const float* XtB = Xt + (size_t)b * D * LSEQ;
#pragma unroll
  for (int k2 = 0; k2 < 16; ++k2) {
    const int l = tid + (k2 << 8);
    float mx = fmaxf(fmaxf(Mpart[(size_t)b * LSEQ + l], Mpart[((size_t)NB + b) * LSEQ + l]),
                     fmaxf(Mpart[((size_t)2 * NB + b) * LSEQ + l],
                           Mpart[((size_t)3 * NB + b) * LSEQ + l]));
    float dot = 0.f;
    for (int d = 0; d < D; ++d) dot = fmaf(XtB[(size_t)d * LSEQ + l], ks[d], dot);
    const float v = mx - dot * (1.0f / LSEQ);
    uint32_t u = __float_as_uint(v);
    u ^= (u & 0x80000000u) ? 0xFFFFFFFFu : 0x80000000u;
    kreg[k2] = u;
  }

  // 2. radix select: find exact 45th-largest key T and need (# of T-dups kept)
  const uint32_t pmaskA[4] = {0u, 0xFF000000u, 0xFFFF0000u, 0xFFFFFF00u};
  uint32_t P = 0;
  int need = U;
#pragma unroll
  for (int r = 0; r < 4; ++r) {
    const int shift = 24 - 8 * r;
    hist[tid] = 0;
    __syncthreads();
#pragma unroll
    for (int k2 = 0; k2 < 16; ++k2) {
      const uint32_t key = kreg[k2];
      if (((key ^ P) & pmaskA[r]) == 0) atomicAdd(&hist[(key >> shift) & 0xFF], 1);
    }
    __syncthreads();
    const int h = hist[255 - tid];
    int s = h;
#pragma unroll
    for (int off = 1; off < 64; off <<= 1) {
      int t2 = __shfl_up(s, off);
      if (lane >= off) s += t2;
    }
    if (lane == 63) wsum[wv] = s;
    __syncthreads();
    for (int w2 = 0; w2 < wv; ++w2) s += wsum[w2];
    const int above = s - h;
    if (above < need && s >= need) { bin_s = 255 - tid; need_s = need - above; }
    __syncthreads();
    P |= ((uint32_t)bin_s) << shift;
    need = need_s;
    __syncthreads();
  }
  const uint32_t T = P;

  // 3. collect strictly-greater keys + equal-key indices
  if (tid == 0) { cntG_s = 0; cntEq_s = 0; }
  __syncthreads();
#pragma unroll
  for (int k2 = 0; k2 < 16; ++k2) {
    const uint32_t key = kreg[k2];
    const int l = tid + (k2 << 8);
    if (key > T) {
      int p = atomicAdd(&cntG_s, 1);
      cand[p] = ((unsigned long long)key << 32) | (unsigned long long)(4095 - l);
    } else if (key == T) {
      int p = atomicAdd(&cntEq_s, 1);
      eqIdx[p] = l;
    }
  }
  __syncthreads();
  const int G = cntG_s;
  const int nEq = cntEq_s;
  for (int j = 0; j < need; ++j) {
    int mv2 = 0x7FFFFFFF;
    for (int i = tid; i < nEq; i += 256) mv2 = min(mv2, eqIdx[i]);
#pragma unroll
    for (int off = 32; off; off >>= 1) mv2 = min(mv2, __shfl_xor(mv2, off));
    if (lane == 0) wsum[wv] = mv2;
    __syncthreads();
    if (tid == 0) {
      int m2 = min(min(wsum[0], wsum[1]), min(wsum[2], wsum[3]));
      cand[G + j] = ((unsigned long long)T << 32) | (unsigned long long)(4095 - m2);
      minv_s = m2;
    }
    __syncthreads();
    for (int i = tid; i < nEq; i += 256)
      if (eqIdx[i] == minv_s) eqIdx[i] = 0x7FFFFFFF;
    __syncthreads();
  }

  // 4. rank sort (value desc, index asc) — packed keys are unique
  if (tid < U) {
    const unsigned long long cu = cand[tid];
    int rank = 0;
    for (int v2 = 0; v2 < U; ++v2) rank += (cand[v2] > cu);
    sel[rank] = 4095 - (int)(cu & 0xFFFFFFFFull);
  }
  __syncthreads();

  // 5. gather selected Q rows
  const float* xb = x + (size_t)b * LSEQ * D;
  for (int i = tid; i < U * D; i += 256) {
    int u2 = i / D, d = i - u2 * D;
    Qg[(size_t)b * U * D + i] = xb[(size_t)sel[u2] * D + d];
  }
}

// ---------------------------------------------------------------------------
// Kernel 5: sparse attention, chunked-parallel (unchanged from round 2).
// ---------------------------------------------------------------------------
__global__ void attn_pv_kernel(const float* __restrict__ x, const float* __restrict__ Qg,
                               float* __restrict__ PVpart) {
  __shared__ float Xs[256][D + 2];
  __shared__ float eS[256][U + 1];
  const int chunk = blockIdx.x, b = blockIdx.y;
  const int tid = threadIdx.x;
  const int l0 = chunk * 256;
  const float* xb = x + ((size_t)b * LSEQ + l0) * D;
  for (int i = tid; i < 256 * D; i += 256) {
    int l = i / D, d = i - l * D;
    Xs[l][d] = xb[i];
  }
  Xs[tid][D] = 1.0f;
  __syncthreads();

  float xr[D];
#pragma unroll
  for (int d = 0; d < D; ++d) xr[d] = Xs[tid][d];
  const float scale = 0.14907119849998599f;  // 1/sqrt(45)
  const float* qb = Qg + (size_t)b * U * D;
  for (int u = 0; u < U; ++u) {
    float acc = 0.f;
#pragma unroll
    for (int d = 0; d < D; ++d) acc = fmaf(qb[u * D + d], xr[d], acc);
    eS[tid][u] = __expf(acc * scale);
  }
  __syncthreads();

  float* outp = PVpart + (size_t)(b * 16 + chunk) * (U * (D + 1));
  for (int idx = tid; idx < U * (D + 1); idx += 256) {
    int u = idx / (D + 1), c = idx - u * (D + 1);
    float acc = 0.f;
#pragma unroll 4
    for (int l = 0; l < 256; ++l) acc = fmaf(eS[l][u], Xs[l][c], acc);
    outp[idx] = acc;
  }
}

// ---------------------------------------------------------------------------
// Kernel 6: combine PV partials -> LN1 -> FFN -> LN2 -> out (unchanged).
// ---------------------------------------------------------------------------
__global__ void epilogue_kernel(const float* __restrict__ PVpart,
                                const float* __restrict__ W1, const float* __restrict__ b1,
                                const float* __restrict__ W2, const float* __restrict__ b2,
                                const float* __restrict__ g1, const float* __restrict__ be1,
                                const float* __restrict__ g2, const float* __restrict__ be2,
                                float* __restrict__ out) {
  __shared__ float hA[D][46];
  __shared__ float den[U];
  __shared__ float Wbuf[FH * D];
  __shared__ float f1s[D][FH + 1];
  __shared__ float f2T[D][46];
  const int b = blockIdx.x;
  const int tid = threadIdx.x;
  const float* PV = PVpart + (size_t)b * 16 * U * (D + 1);
  if (tid < U) {
    float s = 0.f;
    for (int c = 0; c < 16; ++c) s += PV[(size_t)c * U * (D + 1) + tid * (D + 1) + D];
    den[tid] = 1.0f / s;
  }
  for (int i = tid; i < FH * D; i += 256) Wbuf[i] = W1[i];
  __syncthreads();
  for (int i = tid; i < U * D; i += 256) {
    int u = i / D, d = i - u * D;
    float s = 0.f;
    for (int c = 0; c < 16; ++c) s += PV[(size_t)c * U * (D + 1) + u * (D + 1) + d];
    hA[u][d] = s * den[u];
  }
  __syncthreads();
  if (tid < U) {
    const int u = tid;
    float mean = 0.f;
    for (int d = 0; d < D; ++d) mean += hA[u][d];
    mean *= (1.0f / D);
    float var = 0.f;
    for (int d = 0; d < D; ++d) { float t = hA[u][d] - mean; var += t * t; }
    var *= (1.0f / D);
    const float inv = 1.0f / sqrtf(var + LN_EPS);
    for (int d = 0; d < D; ++d) hA[u][d] = g1[d] * ((hA[u][d] - mean) * inv) + be1[d];
  }
  __syncthreads();
  for (int i = tid; i < D * FH; i += 256) {
    const int d = i >> 7, hh = i & 127;
    float acc = b1[hh];
    for (int uu = 0; uu < U; ++uu) acc = fmaf(hA[uu][d], Wbuf[hh * D + uu], acc);
    f1s[d][hh] = fmaxf(acc, 0.f);
  }
  __syncthreads();
  for (int i = tid; i < U * FH; i += 256) Wbuf[i] = W2[i];
  __syncthreads();
  for (int i = tid; i < U * D; i += 256) {
    const int u = i / D, d = i - u * D;
    float acc = b2[u];
    for (int h = 0; h < FH; ++h) acc = fmaf(f1s[d][h], Wbuf[u * FH + h], acc);
    f2T[u][d] = acc;
  }
  __syncthreads();
  if (tid < U) {
    const int u = tid;
    float mean = 0.f;
    for (int d = 0; d < D; ++d) mean += f2T[u][d];
    mean *= (1.0f / D);
    float var = 0.f;
    for (int d = 0; d < D; ++d) { float t = f2T[u][d] - mean; var += t * t; }
    var *= (1.0f / D);
    const float inv = 1.0f / sqrtf(var + LN_EPS);
    float* ob = out + ((size_t)b * U + u) * D;
    for (int d = 0; d < D; ++d) ob[d] = g2[d] * ((f2T[u][d] - mean) * inv) + be2[d];
  }
}

// ---------------------------------------------------------------------------
extern "C" void kernel_launch(void* const* d_in, const int* in_sizes, int n_in,
                              void* d_out, int out_size, void* d_ws, size_t ws_size,
                              hipStream_t stream) {
  const float* x = (const float*)d_in[0];
  const float* W1 = (const float*)d_in[1];
  const float* b1 = (const float*)d_in[2];
  const float* W2 = (const float*)d_in[3];
  const float* b2 = (const float*)d_in[4];
  const float* g1 = (const float*)d_in[5];
  const float* be1 = (const float*)d_in[6];
  const float* g2 = (const float*)d_in[7];
  const float* be2 = (const float*)d_in[8];
  const int* idx = (const int*)d_in[9];
  float* out = (float*)d_out;

  // ws layout (floats): Xt | Ksm | Ksum | Mpart | Qg | PVpart  (~13.9 MiB)
  char* w = (char*)d_ws;
  float* Xt = (float*)w;
  float* Ksm = Xt + (size_t)NB * D * LSEQ;
  float* Ksum = Ksm + (size_t)NB * LSEQ * KP;
  float* Mpart = Ksum + 1024;
  float* Qg = Mpart + (size_t)SPLIT * NB * LSEQ;
  float* PVpart = Qg + (size_t)NB * U * D + 64;

  transpose_kernel<<<dim3(LSEQ / 64, NB, 2), 256, 0, stream>>>(x, idx, Xt, Ksm);
  ksum_kernel<<<dim3(NB), 256, 0, stream>>>(Ksm, Ksum);
  qkmax_kernel<<<dim3(LSEQ / 128, NB, SPLIT), 256, 0, stream>>>(Xt, Ksm, Mpart);
  topk_kernel<<<dim3(NB), 256, 0, stream>>>(x, Xt, Ksum, Mpart, Qg);
  attn_pv_kernel<<<dim3(16, NB), 256, 0, stream>>>(x, Qg, PVpart);
  epilogue_kernel<<<dim3(NB), 256, 0, stream>>>(PVpart, W1, b1, W2, b2, g1, be1, g2, be2, out);
}